// Round 6
// baseline (590.911 us; speedup 1.0000x reference)
//
#include <hip/hip_runtime.h>
#include <hip/hip_bf16.h>

#define NNODES 50000
#define NEDGES 800000
#define ETOT   (NNODES + NEDGES)
#define MTILES 3136            // row-tiles of 16: covers 50176 rows
#define MPAD   (MTILES * 16)   // 50176
#define NBLK   196             // ceil(NNODES/256) for the scan

typedef __attribute__((ext_vector_type(8))) short short8;
typedef __attribute__((ext_vector_type(4))) float floatx4;
typedef __attribute__((ext_vector_type(2))) unsigned int uint2v;

__device__ __forceinline__ float bf2f(__hip_bfloat16 x) { return __bfloat162float(x); }
__device__ __forceinline__ __hip_bfloat16 f2bf(float f) { return __float2bfloat16(f); }
__device__ __forceinline__ float sane(float v, float c) {
  v = (v == v) ? v : 0.f;
  return fminf(fmaxf(v, -c), c);
}
// edge weight: exp(clamp(leakyrelu(logit))) — identical math to the old alpha kernel
__device__ __forceinline__ float edgew(float e) {
  e = e > 0.f ? e : 0.2f * e;
  e = fminf(fmaxf(e, -80.f), 80.f);
  return __expf(e);
}

// ---------------- utility ----------------
__global__ void zero_int_kernel(int* __restrict__ p, int n) {
  int i = blockIdx.x * blockDim.x + threadIdx.x;
  if (i < n) p[i] = 0;
}
__global__ void fill_out_kernel(float* __restrict__ o, int n, float v) {
  int i = blockIdx.x * blockDim.x + threadIdx.x;
  if (i < n) o[i] = v;
}
__global__ void split_input_kernel(const float* __restrict__ in,
                                   __hip_bfloat16* __restrict__ hi,
                                   __hip_bfloat16* __restrict__ lo, int n) {
  int i = blockIdx.x * blockDim.x + threadIdx.x;
  if (i >= n) return;
  float v = sane(in[i], 1e4f);
  __hip_bfloat16 h = f2bf(v);
  hi[i] = h;
  lo[i] = f2bf(v - bf2f(h));
}
// zero the A-buffer tail so pad-row reads (any stride 128/256) see zeros
__global__ void zero_tail_kernel(__hip_bfloat16* __restrict__ hi,
                                 __hip_bfloat16* __restrict__ lo) {
  const int base = NNODES * 128;
  const int cnt = MPAD * 256 - base;
  int i = blockIdx.x * blockDim.x + threadIdx.x;
  if (i >= cnt) return;
  hi[base + i] = f2bf(0.f);
  lo[base + i] = f2bf(0.f);
}
// pad 47-vec attention params to 64 with zeros
__global__ void pad47_kernel(const float* __restrict__ a, const float* __restrict__ b,
                             float* __restrict__ ap, float* __restrict__ bp) {
  int i = threadIdx.x;  // 64
  ap[i] = (i < 47) ? sane(a[i], 1e4f) : 0.f;
  bp[i] = (i < 47) ? sane(b[i], 1e4f) : 0.f;
}

// ---------------- CSR build (dst-sorted) ----------------
__global__ void degree_kernel(const int* __restrict__ ei, int* __restrict__ deg) {
  int p = blockIdx.x * blockDim.x + threadIdx.x;
  if (p >= ETOT) return;
  int dst = (p < NEDGES) ? ei[NEDGES + p] : (p - NEDGES);
  dst = min(max(dst, 0), NNODES - 1);
  atomicAdd(&deg[dst], 1);
}

// --- parallel 3-phase scan ---
__global__ __launch_bounds__(256) void block_sum_kernel(const int* __restrict__ deg,
                                                        int* __restrict__ bsum) {
  __shared__ int sh[256];
  int b = blockIdx.x, t = threadIdx.x;
  int i = b * 256 + t;
  sh[t] = (i < NNODES) ? deg[i] : 0;
  __syncthreads();
  for (int off = 128; off > 0; off >>= 1) {
    if (t < off) sh[t] += sh[t + off];
    __syncthreads();
  }
  if (t == 0) bsum[b] = sh[0];
}

__global__ __launch_bounds__(256) void scan_bsum_kernel(const int* __restrict__ bsum,
                                                        int* __restrict__ boff,
                                                        int* __restrict__ row_ptr) {
  __shared__ int sh[256];
  int t = threadIdx.x;
  int v = (t < NBLK) ? bsum[t] : 0;
  sh[t] = v;
  __syncthreads();
  for (int off = 1; off < 256; off <<= 1) {
    int u = (t >= off) ? sh[t - off] : 0;
    __syncthreads();
    sh[t] += u;
    __syncthreads();
  }
  if (t < NBLK) boff[t] = sh[t] - v;  // exclusive block offset
  if (t == 255) row_ptr[NNODES] = sh[255];
}

__global__ __launch_bounds__(256) void emit_rowptr_kernel(const int* __restrict__ deg,
                                                          const int* __restrict__ boff,
                                                          int* __restrict__ row_ptr,
                                                          int* __restrict__ cursor) {
  __shared__ int sh[256];
  int b = blockIdx.x, t = threadIdx.x;
  int i = b * 256 + t;
  int d = (i < NNODES) ? deg[i] : 0;
  sh[t] = d;
  __syncthreads();
  for (int off = 1; off < 256; off <<= 1) {
    int u = (t >= off) ? sh[t - off] : 0;
    __syncthreads();
    sh[t] += u;
    __syncthreads();
  }
  if (i < NNODES) {
    int v = boff[b] + sh[t] - d;  // exclusive prefix
    row_ptr[i] = v;
    cursor[i] = v;
  }
}

__global__ void scatter_kernel(const int* __restrict__ ei, int* __restrict__ cursor,
                               int* __restrict__ csr_src) {
  int p = blockIdx.x * blockDim.x + threadIdx.x;
  if (p >= ETOT) return;
  int src, dst;
  if (p < NEDGES) { src = ei[p]; dst = ei[NEDGES + p]; }
  else            { src = p - NEDGES; dst = src; }
  src = min(max(src, 0), NNODES - 1);
  dst = min(max(dst, 0), NNODES - 1);
  int pos = atomicAdd(&cursor[dst], 1);
  pos = min(max(pos, 0), ETOT - 1);
  csr_src[pos] = src;
}

// ---------------- weight pack (W [K][Nreal] f32 -> fragment-packed W^T) -------
__global__ void pack_w_kernel(const float* __restrict__ W,
                              __hip_bfloat16* __restrict__ Bh,
                              __hip_bfloat16* __restrict__ Bl,
                              int K, int Nreal, int Npad) {
  int idx = blockIdx.x * blockDim.x + threadIdx.x;
  if (idx >= Npad * K) return;
  int e = idx;
  int j = e & 7;    e >>= 3;
  int m = e & 15;   e >>= 4;
  int quad = e & 3; e >>= 2;
  int kch = K >> 5;
  int kk32 = e % kch;
  int nt = e / kch;
  int n = nt * 16 + m;
  int k = kk32 * 32 + quad * 8 + j;
  float v = (n < Nreal) ? sane(W[k * Nreal + n], 1e4f) : 0.f;
  __hip_bfloat16 h = f2bf(v);
  Bh[idx] = h;
  Bl[idx] = f2bf(v - bf2f(h));
}

// ---------------- GEMM + fused attention logits (verified bit-exact) --------
template<int KDIM, int NOUT, int HEADS, int WAVES_N>
__global__ __launch_bounds__(256) void gemm_attn_kernel(
    const __hip_bfloat16* __restrict__ Ah, const __hip_bfloat16* __restrict__ Al,
    const __hip_bfloat16* __restrict__ Bh, const __hip_bfloat16* __restrict__ Bl,
    const float* __restrict__ asv, const float* __restrict__ adv,
    __hip_bfloat16* __restrict__ Ch, float* __restrict__ als, float* __restrict__ ald) {
  constexpr int KCH = KDIM / 32;
  constexpr int CT = (NOUT / 16) / WAVES_N;  // 4
  constexpr int RT = 4;
  constexpr int RGROUPS = 4 / WAVES_N;       // row groups per block
  __shared__ __hip_bfloat16 sAh[64 * 32];
  __shared__ __hip_bfloat16 sAl[64 * 32];
  int wave = threadIdx.x >> 6, lane = threadIdx.x & 63;
  int wrow = wave / WAVES_N, wcol = wave % WAVES_N;
  int rt0 = (blockIdx.x * RGROUPS + wrow) * RT;
  int ct0 = wcol * CT;
  int m = lane & 15, quad = lane >> 4;

  const short8* Bph = reinterpret_cast<const short8*>(Bh);
  const short8* Bpl = reinterpret_cast<const short8*>(Bl);

  floatx4 acc[RT][CT];
#pragma unroll
  for (int rt = 0; rt < RT; ++rt)
#pragma unroll
    for (int ct = 0; ct < CT; ++ct) acc[rt][ct] = (floatx4){0.f, 0.f, 0.f, 0.f};

  int tid = threadIdx.x;
  size_t gstage = (size_t)(rt0 * 16 + (tid >> 2)) * KDIM + (tid & 3) * 8;

#pragma unroll 2
  for (int kk = 0; kk < KCH; ++kk) {
    short8 a_h[RT], a_l[RT];
    if constexpr (WAVES_N == 4) {
      short8 vh = *reinterpret_cast<const short8*>(Ah + gstage + kk * 32);
      short8 vl = *reinterpret_cast<const short8*>(Al + gstage + kk * 32);
      __syncthreads();  // prior kk's reads complete before overwrite
      *reinterpret_cast<short8*>(&sAh[tid * 8]) = vh;
      *reinterpret_cast<short8*>(&sAl[tid * 8]) = vl;
      __syncthreads();
#pragma unroll
      for (int rt = 0; rt < RT; ++rt) {
        int so = (rt * 16 + m) * 32 + quad * 8;
        a_h[rt] = *reinterpret_cast<const short8*>(&sAh[so]);
        a_l[rt] = *reinterpret_cast<const short8*>(&sAl[so]);
      }
    } else {
#pragma unroll
      for (int rt = 0; rt < RT; ++rt) {
        size_t aoff = (size_t)((rt0 + rt) * 16 + m) * KDIM + kk * 32 + quad * 8;
        a_h[rt] = *reinterpret_cast<const short8*>(Ah + aoff);
        a_l[rt] = *reinterpret_cast<const short8*>(Al + aoff);
      }
    }
#pragma unroll
    for (int ct = 0; ct < CT; ++ct) {
      size_t o = ((size_t)(ct0 + ct) * KCH + kk) * 64 + lane;
      short8 b_h = Bph[o];
      short8 b_l = Bpl[o];
#pragma unroll
      for (int rt = 0; rt < RT; ++rt) {
        acc[rt][ct] = __builtin_amdgcn_mfma_f32_16x16x32_bf16(a_h[rt], b_h, acc[rt][ct], 0, 0, 0);
        acc[rt][ct] = __builtin_amdgcn_mfma_f32_16x16x32_bf16(a_h[rt], b_l, acc[rt][ct], 0, 0, 0);
        acc[rt][ct] = __builtin_amdgcn_mfma_f32_16x16x32_bf16(a_l[rt], b_h, acc[rt][ct], 0, 0, 0);
      }
    }
  }

  constexpr int CPH = NOUT / HEADS;
  int head = (ct0 * 16) / CPH;
  float asl[CT], adl[CT];
#pragma unroll
  for (int ct = 0; ct < CT; ++ct) {
    asl[ct] = asv[(ct0 + ct) * 16 + m];
    adl[ct] = adv[(ct0 + ct) * 16 + m];
  }
  float ps[RT * 4], pd[RT * 4];
#pragma unroll
  for (int i = 0; i < RT * 4; ++i) { ps[i] = 0.f; pd[i] = 0.f; }
#pragma unroll
  for (int rt = 0; rt < RT; ++rt)
#pragma unroll
    for (int ct = 0; ct < CT; ++ct)
#pragma unroll
      for (int r = 0; r < 4; ++r) {
        ps[rt * 4 + r] += acc[rt][ct][r] * asl[ct];
        pd[rt * 4 + r] += acc[rt][ct][r] * adl[ct];
      }
#pragma unroll
  for (int off = 1; off < 16; off <<= 1) {
#pragma unroll
    for (int i = 0; i < RT * 4; ++i) {
      ps[i] += __shfl_xor(ps[i], off);
      pd[i] += __shfl_xor(pd[i], off);
    }
  }
  if (m == 0) {
#pragma unroll
    for (int rt = 0; rt < RT; ++rt)
#pragma unroll
      for (int r = 0; r < 4; ++r) {
        int row = (rt0 + rt) * 16 + quad * 4 + r;
        if (row < NNODES) {
          als[(size_t)row * HEADS + head] = sane(ps[rt * 4 + r], 80.f);
          ald[(size_t)row * HEADS + head] = sane(pd[rt * 4 + r], 80.f);
        }
      }
  }

#pragma unroll
  for (int rt = 0; rt < RT; ++rt)
#pragma unroll
    for (int ct = 0; ct < CT; ++ct)
#pragma unroll
      for (int r = 0; r < 4; ++r) {
        int row = (rt0 + rt) * 16 + quad * 4 + r;
        if (row < NNODES) {
          float v = sane(acc[rt][ct][r], 3e4f);
          Ch[(size_t)row * NOUT + (ct0 + ct) * 16 + m] = f2bf(v);
        }
      }
}

// ---------------- aggregation, mid layers (T=256, H=4), softmax fused -------
// phase 1: per-head denominators (thread-per-edge pass, reduce in regs+LDS)
// phase 2: gather with w=exp(clamp(lrelu)) inline, 4 edges in flight/wave;
// normalize once at the end: o = (sum w*f) * inv + bias.
__global__ __launch_bounds__(256) void agg_mid_kernel(const int* __restrict__ row_ptr,
                                                      const int* __restrict__ csr_src,
                                                      const __hip_bfloat16* __restrict__ Fh,
                                                      const float* __restrict__ als,
                                                      const float* __restrict__ ald,
                                                      const float* __restrict__ bias,
                                                      __hip_bfloat16* __restrict__ Oh,
                                                      __hip_bfloat16* __restrict__ Ol) {
  __shared__ float part[4][256];
  __shared__ float sinv[4];
  int dst = blockIdx.x;
  int tid = threadIdx.x, wid = tid >> 6, lane = tid & 63;
  int start = row_ptr[dst], end = row_ptr[dst + 1];
  int cnt = end - start;
  floatx4 adv = *reinterpret_cast<const floatx4*>(ald + (size_t)dst * 4);

  // phase 1: denominators
  float d0 = 0.f, d1 = 0.f, d2 = 0.f, d3 = 0.f;
  for (int p = tid; p < cnt; p += 256) {
    int s = csr_src[start + p];
    floatx4 av = *reinterpret_cast<const floatx4*>(als + (size_t)s * 4);
    d0 += edgew(av.x + adv.x);
    d1 += edgew(av.y + adv.y);
    d2 += edgew(av.z + adv.z);
    d3 += edgew(av.w + adv.w);
  }
#pragma unroll
  for (int off = 1; off < 64; off <<= 1) {
    d0 += __shfl_xor(d0, off);
    d1 += __shfl_xor(d1, off);
    d2 += __shfl_xor(d2, off);
    d3 += __shfl_xor(d3, off);
  }
  if (lane == 0) {
    part[wid][0] = d0; part[wid][1] = d1; part[wid][2] = d2; part[wid][3] = d3;
  }
  __syncthreads();
  if (tid < 4) {
    float ds = part[0][tid] + part[1][tid] + part[2][tid] + part[3][tid];
    sinv[tid] = 1.f / fmaxf(ds, 1e-30f);
  }
  __syncthreads();

  // phase 2: weighted gather
  int head = lane >> 4;
  float adh = (head == 0) ? adv.x : (head == 1) ? adv.y : (head == 2) ? adv.z : adv.w;
  float a0 = 0.f, a1 = 0.f, a2 = 0.f, a3 = 0.f;
  int p = wid;
  for (; p + 12 < cnt; p += 16) {  // 4 edges in flight per wave
    int e0 = start + p, e1 = start + p + 4, e2 = start + p + 8, e3 = start + p + 12;
    int s0 = csr_src[e0], s1 = csr_src[e1], s2 = csr_src[e2], s3 = csr_src[e3];
    float w0 = edgew(als[(size_t)s0 * 4 + head] + adh);
    float w1 = edgew(als[(size_t)s1 * 4 + head] + adh);
    float w2 = edgew(als[(size_t)s2 * 4 + head] + adh);
    float w3 = edgew(als[(size_t)s3 * 4 + head] + adh);
    uint2v f0 = *reinterpret_cast<const uint2v*>(Fh + (size_t)s0 * 256 + lane * 4);
    uint2v f1 = *reinterpret_cast<const uint2v*>(Fh + (size_t)s1 * 256 + lane * 4);
    uint2v f2 = *reinterpret_cast<const uint2v*>(Fh + (size_t)s2 * 256 + lane * 4);
    uint2v f3 = *reinterpret_cast<const uint2v*>(Fh + (size_t)s3 * 256 + lane * 4);
    a0 += w0 * __uint_as_float(f0.x << 16);
    a1 += w0 * __uint_as_float(f0.x & 0xffff0000u);
    a2 += w0 * __uint_as_float(f0.y << 16);
    a3 += w0 * __uint_as_float(f0.y & 0xffff0000u);
    a0 += w1 * __uint_as_float(f1.x << 16);
    a1 += w1 * __uint_as_float(f1.x & 0xffff0000u);
    a2 += w1 * __uint_as_float(f1.y << 16);
    a3 += w1 * __uint_as_float(f1.y & 0xffff0000u);
    a0 += w2 * __uint_as_float(f2.x << 16);
    a1 += w2 * __uint_as_float(f2.x & 0xffff0000u);
    a2 += w2 * __uint_as_float(f2.y << 16);
    a3 += w2 * __uint_as_float(f2.y & 0xffff0000u);
    a0 += w3 * __uint_as_float(f3.x << 16);
    a1 += w3 * __uint_as_float(f3.x & 0xffff0000u);
    a2 += w3 * __uint_as_float(f3.y << 16);
    a3 += w3 * __uint_as_float(f3.y & 0xffff0000u);
  }
  for (; p < cnt; p += 4) {
    int e0 = start + p;
    int s0 = csr_src[e0];
    float w0 = edgew(als[(size_t)s0 * 4 + head] + adh);
    uint2v f0 = *reinterpret_cast<const uint2v*>(Fh + (size_t)s0 * 256 + lane * 4);
    a0 += w0 * __uint_as_float(f0.x << 16);
    a1 += w0 * __uint_as_float(f0.x & 0xffff0000u);
    a2 += w0 * __uint_as_float(f0.y << 16);
    a3 += w0 * __uint_as_float(f0.y & 0xffff0000u);
  }
  *reinterpret_cast<floatx4*>(&part[wid][lane * 4]) = (floatx4){a0, a1, a2, a3};
  __syncthreads();
  int t = tid;
  float o = (part[0][t] + part[1][t] + part[2][t] + part[3][t]) * sinv[t >> 6] + bias[t];
  o = o > 0.f ? o : __expf(o) - 1.f;  // ELU
  __hip_bfloat16 h = f2bf(o);
  Oh[(size_t)dst * 256 + t] = h;
  Ol[(size_t)dst * 256 + t] = f2bf(o - bf2f(h));
}

// ---------------- aggregation, final layer (H=1), softmax fused -------------
__global__ void agg_final_kernel(const int* __restrict__ row_ptr,
                                 const int* __restrict__ csr_src,
                                 const __hip_bfloat16* __restrict__ Fh,
                                 const float* __restrict__ als,
                                 const float* __restrict__ ald,
                                 const float* __restrict__ bias,
                                 float* __restrict__ out) {
  int wid = threadIdx.x >> 6, lane = threadIdx.x & 63;
  int dst = blockIdx.x * 4 + wid;
  if (dst >= NNODES) return;
  int start = row_ptr[dst], end = row_ptr[dst + 1];
  int cnt = end - start;
  float adh = ald[dst];
  // phase 1: denominator (lane-per-edge)
  float d = 0.f;
  for (int p = lane; p < cnt; p += 64) d += edgew(als[csr_src[start + p]] + adh);
#pragma unroll
  for (int off = 1; off < 64; off <<= 1) d += __shfl_xor(d, off);
  float inv = 1.f / fmaxf(d, 1e-30f);
  // phase 2: weighted gather
  float acc = 0.f;
  int e = start;
  for (; e + 1 < end; e += 2) {
    int s0 = csr_src[e], s1 = csr_src[e + 1];
    float w0 = edgew(als[s0] + adh);
    float w1 = edgew(als[s1] + adh);
    float f0 = bf2f(Fh[(size_t)s0 * 64 + lane]);
    float f1 = bf2f(Fh[(size_t)s1 * 64 + lane]);
    acc += w0 * f0 + w1 * f1;
  }
  for (; e < end; ++e) {
    int s0 = csr_src[e];
    acc += edgew(als[s0] + adh) * bf2f(Fh[(size_t)s0 * 64 + lane]);
  }
  if (lane < 47) out[(size_t)dst * 47 + lane] = acc * inv + bias[lane];
}

// ---------------- launch ----------------
extern "C" void kernel_launch(void* const* d_in, const int* in_sizes, int n_in,
                              void* d_out, int out_size, void* d_ws, size_t ws_size,
                              hipStream_t stream) {
  const float* x   = (const float*)d_in[0];
  const int* ei    = (const int*)d_in[1];
  const float* W1  = (const float*)d_in[2];
  const float* a1s = (const float*)d_in[3];
  const float* a1d = (const float*)d_in[4];
  const float* b1  = (const float*)d_in[5];
  const float* W2  = (const float*)d_in[6];
  const float* a2s = (const float*)d_in[7];
  const float* a2d = (const float*)d_in[8];
  const float* b2  = (const float*)d_in[9];
  const float* W3  = (const float*)d_in[10];
  const float* a3s = (const float*)d_in[11];
  const float* a3d = (const float*)d_in[12];
  const float* b3  = (const float*)d_in[13];
  float* out = (float*)d_out;
  (void)n_in; (void)in_sizes;

  char* base = (char*)d_ws;
  size_t off = 0;
  auto alloc = [&](size_t bytes) -> char* {
    off = (off + 255) & ~(size_t)255;
    char* p = base + off;
    off += bytes;
    return p;
  };
  int* deg     = (int*)alloc((size_t)NNODES * 4);
  int* cursor  = (int*)alloc((size_t)NNODES * 4);
  int* row_ptr = (int*)alloc((size_t)(NNODES + 1) * 4);
  int* csr_src = (int*)alloc((size_t)ETOT * 4);
  int* bsum    = (int*)alloc(256 * 4);
  int* boff    = (int*)alloc(256 * 4);
  float* als   = (float*)alloc((size_t)NNODES * 4 * 4);
  float* ald   = (float*)alloc((size_t)NNODES * 4 * 4);
  __hip_bfloat16* Ah = (__hip_bfloat16*)alloc((size_t)MPAD * 256 * 2);
  __hip_bfloat16* Al = (__hip_bfloat16*)alloc((size_t)MPAD * 256 * 2);
  __hip_bfloat16* Fh = (__hip_bfloat16*)alloc((size_t)NNODES * 256 * 2);
  __hip_bfloat16* wth = (__hip_bfloat16*)alloc((size_t)256 * 256 * 2);
  __hip_bfloat16* wtl = (__hip_bfloat16*)alloc((size_t)256 * 256 * 2);
  float* asv3 = (float*)alloc(64 * 4);
  float* adv3 = (float*)alloc(64 * 4);

  if (ws_size < off) {
    fill_out_kernel<<<(out_size + 255) / 256, 256, 0, stream>>>(out, out_size, 12345.f);
    return;
  }

  // CSR build (shared by all layers) — parallel 3-phase scan
  zero_int_kernel<<<(NNODES + 255) / 256, 256, 0, stream>>>(deg, NNODES);
  degree_kernel<<<(ETOT + 255) / 256, 256, 0, stream>>>(ei, deg);
  block_sum_kernel<<<NBLK, 256, 0, stream>>>(deg, bsum);
  scan_bsum_kernel<<<1, 256, 0, stream>>>(bsum, boff, row_ptr);
  emit_rowptr_kernel<<<NBLK, 256, 0, stream>>>(deg, boff, row_ptr, cursor);
  scatter_kernel<<<(ETOT + 255) / 256, 256, 0, stream>>>(ei, cursor, csr_src);

  split_input_kernel<<<(NNODES * 128 + 255) / 256, 256, 0, stream>>>(x, Ah, Al, NNODES * 128);
  {
    const int tail = MPAD * 256 - NNODES * 128;
    zero_tail_kernel<<<(tail + 255) / 256, 256, 0, stream>>>(Ah, Al);
  }
  pad47_kernel<<<1, 64, 0, stream>>>(a3s, a3d, asv3, adv3);

  const int grid12 = (NNODES + 63) / 64;       // 782
  const int grid3 = (NNODES + 255) / 256;      // 196

  // layer 1: 128 -> 4x64, ELU
  pack_w_kernel<<<(256 * 128 + 255) / 256, 256, 0, stream>>>(W1, wth, wtl, 128, 256, 256);
  gemm_attn_kernel<128, 256, 4, 4><<<grid12, 256, 0, stream>>>(Ah, Al, wth, wtl, a1s, a1d,
                                                               Fh, als, ald);
  agg_mid_kernel<<<NNODES, 256, 0, stream>>>(row_ptr, csr_src, Fh, als, ald, b1, Ah, Al);

  // layer 2: 256 -> 4x64, ELU
  pack_w_kernel<<<(256 * 256 + 255) / 256, 256, 0, stream>>>(W2, wth, wtl, 256, 256, 256);
  gemm_attn_kernel<256, 256, 4, 4><<<grid12, 256, 0, stream>>>(Ah, Al, wth, wtl, a2s, a2d,
                                                               Fh, als, ald);
  agg_mid_kernel<<<NNODES, 256, 0, stream>>>(row_ptr, csr_src, Fh, als, ald, b2, Ah, Al);

  // layer 3: 256 -> 47 (pad 64), no ELU, fp32 out
  pack_w_kernel<<<(64 * 256 + 255) / 256, 256, 0, stream>>>(W3, wth, wtl, 256, 47, 64);
  gemm_attn_kernel<256, 64, 1, 1><<<grid3, 256, 0, stream>>>(Ah, Al, wth, wtl, asv3, adv3,
                                                             Fh, als, ald);
  agg_final_kernel<<<(NNODES + 3) / 4, 256, 0, stream>>>(row_ptr, csr_src, Fh, als, ald, b3, out);
}

// Round 7
// 542.605 us; speedup vs baseline: 1.0890x; 1.0890x over previous
//
#include <hip/hip_runtime.h>
#include <hip/hip_bf16.h>

#define NNODES 50000
#define NEDGES 800000
#define ETOT   (NNODES + NEDGES)
#define MTILES 3136            // row-tiles of 16: covers 50176 rows
#define MPAD   (MTILES * 16)   // 50176
#define NBLK   196             // ceil(NNODES/256) for the scan

typedef __attribute__((ext_vector_type(8))) short short8;
typedef __attribute__((ext_vector_type(4))) float floatx4;
typedef __attribute__((ext_vector_type(4))) unsigned int uint4v;

__device__ __forceinline__ float bf2f(__hip_bfloat16 x) { return __bfloat162float(x); }
__device__ __forceinline__ __hip_bfloat16 f2bf(float f) { return __float2bfloat16(f); }
__device__ __forceinline__ float sane(float v, float c) {
  v = (v == v) ? v : 0.f;
  return fminf(fmaxf(v, -c), c);
}

// ---------------- utility ----------------
__global__ void zero_int_kernel(int* __restrict__ p, int n) {
  int i = blockIdx.x * blockDim.x + threadIdx.x;
  if (i < n) p[i] = 0;
}
__global__ void fill_out_kernel(float* __restrict__ o, int n, float v) {
  int i = blockIdx.x * blockDim.x + threadIdx.x;
  if (i < n) o[i] = v;
}
// split x into hi/lo bf16 over [0, NNODES*128); zero-fill [NNODES*128, MPAD*256)
__global__ void split_input_kernel(const float* __restrict__ in,
                                   __hip_bfloat16* __restrict__ hi,
                                   __hip_bfloat16* __restrict__ lo) {
  int i = blockIdx.x * blockDim.x + threadIdx.x;
  if (i >= MPAD * 256) return;
  float v = (i < NNODES * 128) ? sane(in[i], 1e4f) : 0.f;
  __hip_bfloat16 h = f2bf(v);
  hi[i] = h;
  lo[i] = f2bf(v - bf2f(h));
}
// pad 47-vec attention params to 64 with zeros
__global__ void pad47_kernel(const float* __restrict__ a, const float* __restrict__ b,
                             float* __restrict__ ap, float* __restrict__ bp) {
  int i = threadIdx.x;  // 64
  ap[i] = (i < 47) ? sane(a[i], 1e4f) : 0.f;
  bp[i] = (i < 47) ? sane(b[i], 1e4f) : 0.f;
}

// ---------------- CSR build (dst-sorted) ----------------
__global__ void degree_kernel(const int* __restrict__ ei, int* __restrict__ deg) {
  int p = blockIdx.x * blockDim.x + threadIdx.x;
  if (p >= ETOT) return;
  int dst = (p < NEDGES) ? ei[NEDGES + p] : (p - NEDGES);
  dst = min(max(dst, 0), NNODES - 1);
  atomicAdd(&deg[dst], 1);
}

// --- parallel 3-phase scan ---
__global__ __launch_bounds__(256) void block_sum_kernel(const int* __restrict__ deg,
                                                        int* __restrict__ bsum) {
  __shared__ int sh[256];
  int b = blockIdx.x, t = threadIdx.x;
  int i = b * 256 + t;
  sh[t] = (i < NNODES) ? deg[i] : 0;
  __syncthreads();
  for (int off = 128; off > 0; off >>= 1) {
    if (t < off) sh[t] += sh[t + off];
    __syncthreads();
  }
  if (t == 0) bsum[b] = sh[0];
}

__global__ __launch_bounds__(256) void scan_bsum_kernel(const int* __restrict__ bsum,
                                                        int* __restrict__ boff,
                                                        int* __restrict__ row_ptr) {
  __shared__ int sh[256];
  int t = threadIdx.x;
  int v = (t < NBLK) ? bsum[t] : 0;
  sh[t] = v;
  __syncthreads();
  for (int off = 1; off < 256; off <<= 1) {
    int u = (t >= off) ? sh[t - off] : 0;
    __syncthreads();
    sh[t] += u;
    __syncthreads();
  }
  if (t < NBLK) boff[t] = sh[t] - v;  // exclusive block offset
  if (t == 255) row_ptr[NNODES] = sh[255];
}

__global__ __launch_bounds__(256) void emit_rowptr_kernel(const int* __restrict__ deg,
                                                          const int* __restrict__ boff,
                                                          int* __restrict__ row_ptr,
                                                          int* __restrict__ cursor) {
  __shared__ int sh[256];
  int b = blockIdx.x, t = threadIdx.x;
  int i = b * 256 + t;
  int d = (i < NNODES) ? deg[i] : 0;
  sh[t] = d;
  __syncthreads();
  for (int off = 1; off < 256; off <<= 1) {
    int u = (t >= off) ? sh[t - off] : 0;
    __syncthreads();
    sh[t] += u;
    __syncthreads();
  }
  if (i < NNODES) {
    int v = boff[b] + sh[t] - d;  // exclusive prefix
    row_ptr[i] = v;
    cursor[i] = v;
  }
}

__global__ void scatter_kernel(const int* __restrict__ ei, int* __restrict__ cursor,
                               int* __restrict__ csr_src) {
  int p = blockIdx.x * blockDim.x + threadIdx.x;
  if (p >= ETOT) return;
  int src, dst;
  if (p < NEDGES) { src = ei[p]; dst = ei[NEDGES + p]; }
  else            { src = p - NEDGES; dst = src; }
  src = min(max(src, 0), NNODES - 1);
  dst = min(max(dst, 0), NNODES - 1);
  int pos = atomicAdd(&cursor[dst], 1);
  pos = min(max(pos, 0), ETOT - 1);
  csr_src[pos] = src;
}

// ---------------- weight pack (W [K][Nreal] f32 -> fragment-packed W^T) -------
__global__ void pack_w_kernel(const float* __restrict__ W,
                              __hip_bfloat16* __restrict__ Bh,
                              __hip_bfloat16* __restrict__ Bl,
                              int K, int Nreal, int Npad) {
  int idx = blockIdx.x * blockDim.x + threadIdx.x;
  if (idx >= Npad * K) return;
  int e = idx;
  int j = e & 7;    e >>= 3;
  int m = e & 15;   e >>= 4;
  int quad = e & 3; e >>= 2;
  int kch = K >> 5;
  int kk32 = e % kch;
  int nt = e / kch;
  int n = nt * 16 + m;
  int k = kk32 * 32 + quad * 8 + j;
  float v = (n < Nreal) ? sane(W[k * Nreal + n], 1e4f) : 0.f;
  __hip_bfloat16 h = f2bf(v);
  Bh[idx] = h;
  Bl[idx] = f2bf(v - bf2f(h));
}

// ---------------- GEMM + fused attention logits ----------------
// A row-major, B fragment-packed, RT=4 x CT register blocking (all verified
// bit-exact). WAVES_N==4: the block's 64 shared A-rows are LDS-staged, TWO
// kk-slices (64x64 panel, 16KB LDS) per barrier pair -> half the barriers of
// R5, 2x wider staging loads. MFMA order identical to R5 (kk ascending).
// WAVES_N==1 (layer 3): direct loads, unchanged.
template<int KDIM, int NOUT, int HEADS, int WAVES_N>
__global__ __launch_bounds__(256) void gemm_attn_kernel(
    const __hip_bfloat16* __restrict__ Ah, const __hip_bfloat16* __restrict__ Al,
    const __hip_bfloat16* __restrict__ Bh, const __hip_bfloat16* __restrict__ Bl,
    const float* __restrict__ asv, const float* __restrict__ adv,
    __hip_bfloat16* __restrict__ Ch, float* __restrict__ als, float* __restrict__ ald) {
  constexpr int KCH = KDIM / 32;
  constexpr int CT = (NOUT / 16) / WAVES_N;  // 4
  constexpr int RT = 4;
  constexpr int RGROUPS = 4 / WAVES_N;       // row groups per block
  __shared__ __hip_bfloat16 sAh[2 * 64 * 32];
  __shared__ __hip_bfloat16 sAl[2 * 64 * 32];
  int wave = threadIdx.x >> 6, lane = threadIdx.x & 63;
  int wrow = wave / WAVES_N, wcol = wave % WAVES_N;
  int rt0 = (blockIdx.x * RGROUPS + wrow) * RT;
  int ct0 = wcol * CT;
  int m = lane & 15, quad = lane >> 4;

  const short8* Bph = reinterpret_cast<const short8*>(Bh);
  const short8* Bpl = reinterpret_cast<const short8*>(Bl);

  floatx4 acc[RT][CT];
#pragma unroll
  for (int rt = 0; rt < RT; ++rt)
#pragma unroll
    for (int ct = 0; ct < CT; ++ct) acc[rt][ct] = (floatx4){0.f, 0.f, 0.f, 0.f};

  int tid = threadIdx.x;
  size_t gstage = (size_t)(rt0 * 16 + (tid >> 2)) * KDIM + (tid & 3) * 8;

#pragma unroll 2
  for (int ks = 0; ks < KCH / 2; ++ks) {
    short8 a_h[RT], a_l[RT];
    if constexpr (WAVES_N == 4) {
      // stage slices 2ks and 2ks+1 together
      short8 vh0 = *reinterpret_cast<const short8*>(Ah + gstage + ks * 64);
      short8 vh1 = *reinterpret_cast<const short8*>(Ah + gstage + ks * 64 + 32);
      short8 vl0 = *reinterpret_cast<const short8*>(Al + gstage + ks * 64);
      short8 vl1 = *reinterpret_cast<const short8*>(Al + gstage + ks * 64 + 32);
      __syncthreads();  // prior stage's reads complete before overwrite
      *reinterpret_cast<short8*>(&sAh[tid * 8]) = vh0;
      *reinterpret_cast<short8*>(&sAh[2048 + tid * 8]) = vh1;
      *reinterpret_cast<short8*>(&sAl[tid * 8]) = vl0;
      *reinterpret_cast<short8*>(&sAl[2048 + tid * 8]) = vl1;
      __syncthreads();
#pragma unroll
      for (int kk0 = 0; kk0 < 2; ++kk0) {
#pragma unroll
        for (int rt = 0; rt < RT; ++rt) {
          int so = kk0 * 2048 + (rt * 16 + m) * 32 + quad * 8;
          a_h[rt] = *reinterpret_cast<const short8*>(&sAh[so]);
          a_l[rt] = *reinterpret_cast<const short8*>(&sAl[so]);
        }
        int kk = ks * 2 + kk0;
#pragma unroll
        for (int ct = 0; ct < CT; ++ct) {
          size_t o = ((size_t)(ct0 + ct) * KCH + kk) * 64 + lane;
          short8 b_h = Bph[o];
          short8 b_l = Bpl[o];
#pragma unroll
          for (int rt = 0; rt < RT; ++rt) {
            acc[rt][ct] = __builtin_amdgcn_mfma_f32_16x16x32_bf16(a_h[rt], b_h, acc[rt][ct], 0, 0, 0);
            acc[rt][ct] = __builtin_amdgcn_mfma_f32_16x16x32_bf16(a_h[rt], b_l, acc[rt][ct], 0, 0, 0);
            acc[rt][ct] = __builtin_amdgcn_mfma_f32_16x16x32_bf16(a_l[rt], b_h, acc[rt][ct], 0, 0, 0);
          }
        }
      }
    } else {
#pragma unroll
      for (int kk0 = 0; kk0 < 2; ++kk0) {
        int kk = ks * 2 + kk0;
#pragma unroll
        for (int rt = 0; rt < RT; ++rt) {
          size_t aoff = (size_t)((rt0 + rt) * 16 + m) * KDIM + kk * 32 + quad * 8;
          a_h[rt] = *reinterpret_cast<const short8*>(Ah + aoff);
          a_l[rt] = *reinterpret_cast<const short8*>(Al + aoff);
        }
#pragma unroll
        for (int ct = 0; ct < CT; ++ct) {
          size_t o = ((size_t)(ct0 + ct) * KCH + kk) * 64 + lane;
          short8 b_h = Bph[o];
          short8 b_l = Bpl[o];
#pragma unroll
          for (int rt = 0; rt < RT; ++rt) {
            acc[rt][ct] = __builtin_amdgcn_mfma_f32_16x16x32_bf16(a_h[rt], b_h, acc[rt][ct], 0, 0, 0);
            acc[rt][ct] = __builtin_amdgcn_mfma_f32_16x16x32_bf16(a_h[rt], b_l, acc[rt][ct], 0, 0, 0);
            acc[rt][ct] = __builtin_amdgcn_mfma_f32_16x16x32_bf16(a_l[rt], b_h, acc[rt][ct], 0, 0, 0);
          }
        }
      }
    }
  }

  // fused attention logits: this wave's CT*16 cols lie in exactly one head
  constexpr int CPH = NOUT / HEADS;
  int head = (ct0 * 16) / CPH;
  float asl[CT], adl[CT];
#pragma unroll
  for (int ct = 0; ct < CT; ++ct) {
    asl[ct] = asv[(ct0 + ct) * 16 + m];
    adl[ct] = adv[(ct0 + ct) * 16 + m];
  }
  float ps[RT * 4], pd[RT * 4];
#pragma unroll
  for (int i = 0; i < RT * 4; ++i) { ps[i] = 0.f; pd[i] = 0.f; }
#pragma unroll
  for (int rt = 0; rt < RT; ++rt)
#pragma unroll
    for (int ct = 0; ct < CT; ++ct)
#pragma unroll
      for (int r = 0; r < 4; ++r) {
        ps[rt * 4 + r] += acc[rt][ct][r] * asl[ct];
        pd[rt * 4 + r] += acc[rt][ct][r] * adl[ct];
      }
#pragma unroll
  for (int off = 1; off < 16; off <<= 1) {
#pragma unroll
    for (int i = 0; i < RT * 4; ++i) {
      ps[i] += __shfl_xor(ps[i], off);
      pd[i] += __shfl_xor(pd[i], off);
    }
  }
  if (m == 0) {
#pragma unroll
    for (int rt = 0; rt < RT; ++rt)
#pragma unroll
      for (int r = 0; r < 4; ++r) {
        int row = (rt0 + rt) * 16 + quad * 4 + r;
        if (row < NNODES) {
          als[(size_t)row * HEADS + head] = sane(ps[rt * 4 + r], 80.f);
          ald[(size_t)row * HEADS + head] = sane(pd[rt * 4 + r], 80.f);
        }
      }
  }

  // store C (hi-only bf16, row-major for the aggregation gather)
#pragma unroll
  for (int rt = 0; rt < RT; ++rt)
#pragma unroll
    for (int ct = 0; ct < CT; ++ct)
#pragma unroll
      for (int r = 0; r < 4; ++r) {
        int row = (rt0 + rt) * 16 + quad * 4 + r;
        if (row < NNODES) {
          float v = sane(acc[rt][ct][r], 3e4f);
          Ch[(size_t)row * NOUT + (ct0 + ct) * 16 + m] = f2bf(v);
        }
      }
}

// ---------------- normalized edge weights (alpha) ----------------
// one wave per dst node; lane-per-edge; shuffle-reduce denominators
template<int H>
__global__ __launch_bounds__(256) void alpha_kernel(const int* __restrict__ row_ptr,
                                                    const int* __restrict__ csr_src,
                                                    const float* __restrict__ als,
                                                    const float* __restrict__ ald,
                                                    float* __restrict__ alpha) {
  int wid = threadIdx.x >> 6, lane = threadIdx.x & 63;
  int dst = blockIdx.x * 4 + wid;
  if (dst >= NNODES) return;
  int start = row_ptr[dst], end = row_ptr[dst + 1];
  int cnt = end - start;
  if (cnt <= 0) return;
  float adv[H];
#pragma unroll
  for (int h = 0; h < H; ++h) adv[h] = ald[(size_t)dst * H + h];

  if (cnt <= 64) {
    int i = start + lane;
    bool valid = lane < cnt;
    int s = valid ? min(max(csr_src[i], 0), NNODES - 1) : 0;
    float w[H];
#pragma unroll
    for (int h = 0; h < H; ++h) {
      float e = als[(size_t)s * H + h] + adv[h];
      e = e > 0.f ? e : 0.2f * e;
      e = fminf(fmaxf(e, -80.f), 80.f);
      w[h] = valid ? __expf(e) : 0.f;
    }
#pragma unroll
    for (int h = 0; h < H; ++h) {
      float v = w[h];
#pragma unroll
      for (int off = 1; off < 64; off <<= 1) v += __shfl_xor(v, off);
      float inv = 1.f / fmaxf(v, 1e-30f);
      if (valid) alpha[(size_t)i * H + h] = w[h] * inv;
    }
  } else {
    float dl[H];
#pragma unroll
    for (int h = 0; h < H; ++h) dl[h] = 0.f;
    for (int base = start; base < end; base += 64) {
      int i = base + lane;
      bool valid = i < end;
      int s = valid ? min(max(csr_src[i], 0), NNODES - 1) : 0;
#pragma unroll
      for (int h = 0; h < H; ++h) {
        float e = als[(size_t)s * H + h] + adv[h];
        e = e > 0.f ? e : 0.2f * e;
        e = fminf(fmaxf(e, -80.f), 80.f);
        float w = valid ? __expf(e) : 0.f;
        dl[h] += w;
        if (valid) alpha[(size_t)i * H + h] = w;
      }
    }
    float inv[H];
#pragma unroll
    for (int h = 0; h < H; ++h) {
      float v = dl[h];
#pragma unroll
      for (int off = 1; off < 64; off <<= 1) v += __shfl_xor(v, off);
      inv[h] = 1.f / fmaxf(v, 1e-30f);
    }
    for (int base = start; base < end; base += 64) {
      int i = base + lane;
      if (i < end)
#pragma unroll
        for (int h = 0; h < H; ++h) alpha[(size_t)i * H + h] *= inv[h];
    }
  }
}

// ---------------- aggregation, mid layers (T=256, H=4) ----------------
// half-wave per edge: 32 lanes x 16B (dwordx4) cover 256 cols, so one wave
// instruction gathers TWO edge rows (vs one 8B row in R5); 2-deep unroll ->
// 4 rows in flight per wave. 8 partials x 256 cols LDS reduce; ELU + hi/lo
// split epilogue.
__global__ __launch_bounds__(256) void agg_mid_kernel(const int* __restrict__ row_ptr,
                                                      const int* __restrict__ csr_src,
                                                      const __hip_bfloat16* __restrict__ Fh,
                                                      const float* __restrict__ alpha,
                                                      const float* __restrict__ bias,
                                                      __hip_bfloat16* __restrict__ Oh,
                                                      __hip_bfloat16* __restrict__ Ol) {
  __shared__ float part[8][256];
  int dst = blockIdx.x;
  int tid = threadIdx.x;
  int wid = tid >> 6, lane = tid & 63;
  int half = lane >> 5, cl = lane & 31;
  int hw = wid * 2 + half;          // 0..7 half-wave id
  int head = cl >> 3;               // cols cl*8..cl*8+7 lie in head cl>>3
  int start = row_ptr[dst], end = row_ptr[dst + 1];
  int cnt = end - start;
  float a[8];
#pragma unroll
  for (int j = 0; j < 8; ++j) a[j] = 0.f;

  int p = hw;
  for (; p + 8 < cnt; p += 16) {  // 2 edges per half-wave in flight
    int e0 = start + p, e1 = start + p + 8;
    int s0 = csr_src[e0], s1 = csr_src[e1];
    float w0 = alpha[(size_t)e0 * 4 + head];
    float w1 = alpha[(size_t)e1 * 4 + head];
    uint4v f0 = *reinterpret_cast<const uint4v*>(Fh + (size_t)s0 * 256 + cl * 8);
    uint4v f1 = *reinterpret_cast<const uint4v*>(Fh + (size_t)s1 * 256 + cl * 8);
    a[0] += w0 * __uint_as_float(f0.x << 16);
    a[1] += w0 * __uint_as_float(f0.x & 0xffff0000u);
    a[2] += w0 * __uint_as_float(f0.y << 16);
    a[3] += w0 * __uint_as_float(f0.y & 0xffff0000u);
    a[4] += w0 * __uint_as_float(f0.z << 16);
    a[5] += w0 * __uint_as_float(f0.z & 0xffff0000u);
    a[6] += w0 * __uint_as_float(f0.w << 16);
    a[7] += w0 * __uint_as_float(f0.w & 0xffff0000u);
    a[0] += w1 * __uint_as_float(f1.x << 16);
    a[1] += w1 * __uint_as_float(f1.x & 0xffff0000u);
    a[2] += w1 * __uint_as_float(f1.y << 16);
    a[3] += w1 * __uint_as_float(f1.y & 0xffff0000u);
    a[4] += w1 * __uint_as_float(f1.z << 16);
    a[5] += w1 * __uint_as_float(f1.z & 0xffff0000u);
    a[6] += w1 * __uint_as_float(f1.w << 16);
    a[7] += w1 * __uint_as_float(f1.w & 0xffff0000u);
  }
  for (; p < cnt; p += 8) {
    int e0 = start + p;
    int s0 = csr_src[e0];
    float w0 = alpha[(size_t)e0 * 4 + head];
    uint4v f0 = *reinterpret_cast<const uint4v*>(Fh + (size_t)s0 * 256 + cl * 8);
    a[0] += w0 * __uint_as_float(f0.x << 16);
    a[1] += w0 * __uint_as_float(f0.x & 0xffff0000u);
    a[2] += w0 * __uint_as_float(f0.y << 16);
    a[3] += w0 * __uint_as_float(f0.y & 0xffff0000u);
    a[4] += w0 * __uint_as_float(f0.z << 16);
    a[5] += w0 * __uint_as_float(f0.z & 0xffff0000u);
    a[6] += w0 * __uint_as_float(f0.w << 16);
    a[7] += w0 * __uint_as_float(f0.w & 0xffff0000u);
  }
  *reinterpret_cast<floatx4*>(&part[hw][cl * 8]) = (floatx4){a[0], a[1], a[2], a[3]};
  *reinterpret_cast<floatx4*>(&part[hw][cl * 8 + 4]) = (floatx4){a[4], a[5], a[6], a[7]};
  __syncthreads();
  int t = tid;
  float o = ((part[0][t] + part[1][t]) + (part[2][t] + part[3][t])) +
            ((part[4][t] + part[5][t]) + (part[6][t] + part[7][t])) + bias[t];
  o = o > 0.f ? o : __expf(o) - 1.f;  // ELU
  __hip_bfloat16 h = f2bf(o);
  Oh[(size_t)dst * 256 + t] = h;
  Ol[(size_t)dst * 256 + t] = f2bf(o - bf2f(h));
}

// ---------------- aggregation, final layer (64-pad feat, 47 out, fp32) ------
__global__ void agg_final_kernel(const int* __restrict__ row_ptr,
                                 const int* __restrict__ csr_src,
                                 const __hip_bfloat16* __restrict__ Fh,
                                 const float* __restrict__ alpha,
                                 const float* __restrict__ bias,
                                 float* __restrict__ out) {
  int wid = threadIdx.x >> 6, lane = threadIdx.x & 63;
  int dst = blockIdx.x * 4 + wid;
  if (dst >= NNODES) return;
  int start = row_ptr[dst], end = row_ptr[dst + 1];
  float acc = 0.f;
  int e = start;
  for (; e + 1 < end; e += 2) {
    int s0 = csr_src[e], s1 = csr_src[e + 1];
    float w0 = alpha[e], w1 = alpha[e + 1];
    float f0 = bf2f(Fh[(size_t)s0 * 64 + lane]);
    float f1 = bf2f(Fh[(size_t)s1 * 64 + lane]);
    acc += w0 * f0 + w1 * f1;
  }
  for (; e < end; ++e) {
    int s0 = csr_src[e];
    acc += alpha[e] * bf2f(Fh[(size_t)s0 * 64 + lane]);
  }
  if (lane < 47) out[(size_t)dst * 47 + lane] = acc + bias[lane];
}

// ---------------- launch ----------------
extern "C" void kernel_launch(void* const* d_in, const int* in_sizes, int n_in,
                              void* d_out, int out_size, void* d_ws, size_t ws_size,
                              hipStream_t stream) {
  const float* x   = (const float*)d_in[0];
  const int* ei    = (const int*)d_in[1];
  const float* W1  = (const float*)d_in[2];
  const float* a1s = (const float*)d_in[3];
  const float* a1d = (const float*)d_in[4];
  const float* b1  = (const float*)d_in[5];
  const float* W2  = (const float*)d_in[6];
  const float* a2s = (const float*)d_in[7];
  const float* a2d = (const float*)d_in[8];
  const float* b2  = (const float*)d_in[9];
  const float* W3  = (const float*)d_in[10];
  const float* a3s = (const float*)d_in[11];
  const float* a3d = (const float*)d_in[12];
  const float* b3  = (const float*)d_in[13];
  float* out = (float*)d_out;
  (void)n_in; (void)in_sizes;

  char* base = (char*)d_ws;
  size_t off = 0;
  auto alloc = [&](size_t bytes) -> char* {
    off = (off + 255) & ~(size_t)255;
    char* p = base + off;
    off += bytes;
    return p;
  };
  int* deg     = (int*)alloc((size_t)NNODES * 4);
  int* cursor  = (int*)alloc((size_t)NNODES * 4);
  int* row_ptr = (int*)alloc((size_t)(NNODES + 1) * 4);
  int* csr_src = (int*)alloc((size_t)ETOT * 4);
  int* bsum    = (int*)alloc(256 * 4);
  int* boff    = (int*)alloc(256 * 4);
  float* als   = (float*)alloc((size_t)NNODES * 4 * 4);
  float* ald   = (float*)alloc((size_t)NNODES * 4 * 4);
  float* alpha = (float*)alloc((size_t)ETOT * 4 * 4);
  __hip_bfloat16* Ah = (__hip_bfloat16*)alloc((size_t)MPAD * 256 * 2);
  __hip_bfloat16* Al = (__hip_bfloat16*)alloc((size_t)MPAD * 256 * 2);
  __hip_bfloat16* Fh = (__hip_bfloat16*)alloc((size_t)NNODES * 256 * 2);
  __hip_bfloat16* wth = (__hip_bfloat16*)alloc((size_t)256 * 256 * 2);
  __hip_bfloat16* wtl = (__hip_bfloat16*)alloc((size_t)256 * 256 * 2);
  float* asv3 = (float*)alloc(64 * 4);
  float* adv3 = (float*)alloc(64 * 4);

  if (ws_size < off) {
    fill_out_kernel<<<(out_size + 255) / 256, 256, 0, stream>>>(out, out_size, 12345.f);
    return;
  }

  // CSR build (shared by all layers) — parallel 3-phase scan
  zero_int_kernel<<<(NNODES + 255) / 256, 256, 0, stream>>>(deg, NNODES);
  degree_kernel<<<(ETOT + 255) / 256, 256, 0, stream>>>(ei, deg);
  block_sum_kernel<<<NBLK, 256, 0, stream>>>(deg, bsum);
  scan_bsum_kernel<<<1, 256, 0, stream>>>(bsum, boff, row_ptr);
  emit_rowptr_kernel<<<NBLK, 256, 0, stream>>>(deg, boff, row_ptr, cursor);
  scatter_kernel<<<(ETOT + 255) / 256, 256, 0, stream>>>(ei, cursor, csr_src);

  split_input_kernel<<<(MPAD * 256 + 255) / 256, 256, 0, stream>>>(x, Ah, Al);
  pad47_kernel<<<1, 64, 0, stream>>>(a3s, a3d, asv3, adv3);

  const int grid12 = (NNODES + 63) / 64;       // 782
  const int grid3 = (NNODES + 255) / 256;      // 196

  // layer 1: 128 -> 4x64, ELU
  pack_w_kernel<<<(256 * 128 + 255) / 256, 256, 0, stream>>>(W1, wth, wtl, 128, 256, 256);
  gemm_attn_kernel<128, 256, 4, 4><<<grid12, 256, 0, stream>>>(Ah, Al, wth, wtl, a1s, a1d,
                                                               Fh, als, ald);
  alpha_kernel<4><<<(NNODES + 3) / 4, 256, 0, stream>>>(row_ptr, csr_src, als, ald, alpha);
  agg_mid_kernel<<<NNODES, 256, 0, stream>>>(row_ptr, csr_src, Fh, alpha, b1, Ah, Al);

  // layer 2: 256 -> 4x64, ELU
  pack_w_kernel<<<(256 * 256 + 255) / 256, 256, 0, stream>>>(W2, wth, wtl, 256, 256, 256);
  gemm_attn_kernel<256, 256, 4, 4><<<grid12, 256, 0, stream>>>(Ah, Al, wth, wtl, a2s, a2d,
                                                               Fh, als, ald);
  alpha_kernel<4><<<(NNODES + 3) / 4, 256, 0, stream>>>(row_ptr, csr_src, als, ald, alpha);
  agg_mid_kernel<<<NNODES, 256, 0, stream>>>(row_ptr, csr_src, Fh, alpha, b2, Ah, Al);

  // layer 3: 256 -> 47 (pad 64), no ELU, fp32 out
  pack_w_kernel<<<(64 * 256 + 255) / 256, 256, 0, stream>>>(W3, wth, wtl, 256, 47, 64);
  gemm_attn_kernel<256, 64, 1, 1><<<grid3, 256, 0, stream>>>(Ah, Al, wth, wtl, asv3, adv3,
                                                             Fh, als, ald);
  alpha_kernel<1><<<(NNODES + 3) / 4, 256, 0, stream>>>(row_ptr, csr_src, als, ald, alpha);
  agg_final_kernel<<<(NNODES + 3) / 4, 256, 0, stream>>>(row_ptr, csr_src, Fh, alpha, b3, out);
}

// Round 8
// 515.766 us; speedup vs baseline: 1.1457x; 1.0520x over previous
//
#include <hip/hip_runtime.h>
#include <hip/hip_bf16.h>

#define NNODES 50000
#define NEDGES 800000
#define ETOT   (NNODES + NEDGES)
#define MTILES 3136            // row-tiles of 16: covers 50176 rows
#define MPAD   (MTILES * 16)   // 50176
#define NBLK   196             // ceil(NNODES/256) for the scan

typedef __attribute__((ext_vector_type(8))) short short8;
typedef __attribute__((ext_vector_type(4))) float floatx4;
typedef __attribute__((ext_vector_type(2))) unsigned int uint2v;
typedef __attribute__((ext_vector_type(4))) short short4v;

__device__ __forceinline__ float bf2f(__hip_bfloat16 x) { return __bfloat162float(x); }
__device__ __forceinline__ __hip_bfloat16 f2bf(float f) { return __float2bfloat16(f); }
__device__ __forceinline__ float sane(float v, float c) {
  v = (v == v) ? v : 0.f;
  return fminf(fmaxf(v, -c), c);
}
__device__ __forceinline__ unsigned short bfbits(float f) {
  union { __hip_bfloat16 b; unsigned short u; } cv;
  cv.b = f2bf(f);
  return cv.u;
}

// ---------------- utility ----------------
__global__ void zero_int_kernel(int* __restrict__ p, int n) {
  int i = blockIdx.x * blockDim.x + threadIdx.x;
  if (i < n) p[i] = 0;
}
__global__ void fill_out_kernel(float* __restrict__ o, int n, float v) {
  int i = blockIdx.x * blockDim.x + threadIdx.x;
  if (i < n) o[i] = v;
}
// split x into hi/lo bf16 over [0, NNODES*128); zero-fill [NNODES*128, MPAD*256)
__global__ void split_input_kernel(const float* __restrict__ in,
                                   __hip_bfloat16* __restrict__ hi,
                                   __hip_bfloat16* __restrict__ lo) {
  int i = blockIdx.x * blockDim.x + threadIdx.x;
  if (i >= MPAD * 256) return;
  float v = (i < NNODES * 128) ? sane(in[i], 1e4f) : 0.f;
  __hip_bfloat16 h = f2bf(v);
  hi[i] = h;
  lo[i] = f2bf(v - bf2f(h));
}
// pad 47-vec attention params to 64 with zeros
__global__ void pad47_kernel(const float* __restrict__ a, const float* __restrict__ b,
                             float* __restrict__ ap, float* __restrict__ bp) {
  int i = threadIdx.x;  // 64
  ap[i] = (i < 47) ? sane(a[i], 1e4f) : 0.f;
  bp[i] = (i < 47) ? sane(b[i], 1e4f) : 0.f;
}

// ---------------- CSR build (dst-sorted) ----------------
__global__ void degree_kernel(const int* __restrict__ ei, int* __restrict__ deg) {
  int p = blockIdx.x * blockDim.x + threadIdx.x;
  if (p >= ETOT) return;
  int dst = (p < NEDGES) ? ei[NEDGES + p] : (p - NEDGES);
  dst = min(max(dst, 0), NNODES - 1);
  atomicAdd(&deg[dst], 1);
}

// --- parallel 3-phase scan ---
__global__ __launch_bounds__(256) void block_sum_kernel(const int* __restrict__ deg,
                                                        int* __restrict__ bsum) {
  __shared__ int sh[256];
  int b = blockIdx.x, t = threadIdx.x;
  int i = b * 256 + t;
  sh[t] = (i < NNODES) ? deg[i] : 0;
  __syncthreads();
  for (int off = 128; off > 0; off >>= 1) {
    if (t < off) sh[t] += sh[t + off];
    __syncthreads();
  }
  if (t == 0) bsum[b] = sh[0];
}

__global__ __launch_bounds__(256) void scan_bsum_kernel(const int* __restrict__ bsum,
                                                        int* __restrict__ boff,
                                                        int* __restrict__ row_ptr) {
  __shared__ int sh[256];
  int t = threadIdx.x;
  int v = (t < NBLK) ? bsum[t] : 0;
  sh[t] = v;
  __syncthreads();
  for (int off = 1; off < 256; off <<= 1) {
    int u = (t >= off) ? sh[t - off] : 0;
    __syncthreads();
    sh[t] += u;
    __syncthreads();
  }
  if (t < NBLK) boff[t] = sh[t] - v;  // exclusive block offset
  if (t == 255) row_ptr[NNODES] = sh[255];
}

__global__ __launch_bounds__(256) void emit_rowptr_kernel(const int* __restrict__ deg,
                                                          const int* __restrict__ boff,
                                                          int* __restrict__ row_ptr,
                                                          int* __restrict__ cursor) {
  __shared__ int sh[256];
  int b = blockIdx.x, t = threadIdx.x;
  int i = b * 256 + t;
  int d = (i < NNODES) ? deg[i] : 0;
  sh[t] = d;
  __syncthreads();
  for (int off = 1; off < 256; off <<= 1) {
    int u = (t >= off) ? sh[t - off] : 0;
    __syncthreads();
    sh[t] += u;
    __syncthreads();
  }
  if (i < NNODES) {
    int v = boff[b] + sh[t] - d;  // exclusive prefix
    row_ptr[i] = v;
    cursor[i] = v;
  }
}

__global__ void scatter_kernel(const int* __restrict__ ei, int* __restrict__ cursor,
                               int* __restrict__ csr_src) {
  int p = blockIdx.x * blockDim.x + threadIdx.x;
  if (p >= ETOT) return;
  int src, dst;
  if (p < NEDGES) { src = ei[p]; dst = ei[NEDGES + p]; }
  else            { src = p - NEDGES; dst = src; }
  src = min(max(src, 0), NNODES - 1);
  dst = min(max(dst, 0), NNODES - 1);
  int pos = atomicAdd(&cursor[dst], 1);
  pos = min(max(pos, 0), ETOT - 1);
  csr_src[pos] = src;
}

// ---------------- weight pack (W [K][Nreal] f32 -> fragment-packed W^T) -------
__global__ void pack_w_kernel(const float* __restrict__ W,
                              __hip_bfloat16* __restrict__ Bh,
                              __hip_bfloat16* __restrict__ Bl,
                              int K, int Nreal, int Npad) {
  int idx = blockIdx.x * blockDim.x + threadIdx.x;
  if (idx >= Npad * K) return;
  int e = idx;
  int j = e & 7;    e >>= 3;
  int m = e & 15;   e >>= 4;
  int quad = e & 3; e >>= 2;
  int kch = K >> 5;
  int kk32 = e % kch;
  int nt = e / kch;
  int n = nt * 16 + m;
  int k = kk32 * 32 + quad * 8 + j;
  float v = (n < Nreal) ? sane(W[k * Nreal + n], 1e4f) : 0.f;
  __hip_bfloat16 h = f2bf(v);
  Bh[idx] = h;
  Bl[idx] = f2bf(v - bf2f(h));
}

// ---------------- GEMM + fused attention logits (verified bit-exact) --------
template<int KDIM, int NOUT, int HEADS, int WAVES_N>
__global__ __launch_bounds__(256) void gemm_attn_kernel(
    const __hip_bfloat16* __restrict__ Ah, const __hip_bfloat16* __restrict__ Al,
    const __hip_bfloat16* __restrict__ Bh, const __hip_bfloat16* __restrict__ Bl,
    const float* __restrict__ asv, const float* __restrict__ adv,
    __hip_bfloat16* __restrict__ Ch, float* __restrict__ als, float* __restrict__ ald) {
  constexpr int KCH = KDIM / 32;
  constexpr int CT = (NOUT / 16) / WAVES_N;  // 4
  constexpr int RT = 4;
  constexpr int RGROUPS = 4 / WAVES_N;       // row groups per block
  __shared__ __hip_bfloat16 sAh[2 * 64 * 32];
  __shared__ __hip_bfloat16 sAl[2 * 64 * 32];
  int wave = threadIdx.x >> 6, lane = threadIdx.x & 63;
  int wrow = wave / WAVES_N, wcol = wave % WAVES_N;
  int rt0 = (blockIdx.x * RGROUPS + wrow) * RT;
  int ct0 = wcol * CT;
  int m = lane & 15, quad = lane >> 4;

  const short8* Bph = reinterpret_cast<const short8*>(Bh);
  const short8* Bpl = reinterpret_cast<const short8*>(Bl);

  floatx4 acc[RT][CT];
#pragma unroll
  for (int rt = 0; rt < RT; ++rt)
#pragma unroll
    for (int ct = 0; ct < CT; ++ct) acc[rt][ct] = (floatx4){0.f, 0.f, 0.f, 0.f};

  int tid = threadIdx.x;
  size_t gstage = (size_t)(rt0 * 16 + (tid >> 2)) * KDIM + (tid & 3) * 8;

#pragma unroll 2
  for (int ks = 0; ks < KCH / 2; ++ks) {
    short8 a_h[RT], a_l[RT];
    if constexpr (WAVES_N == 4) {
      // stage slices 2ks and 2ks+1 together
      short8 vh0 = *reinterpret_cast<const short8*>(Ah + gstage + ks * 64);
      short8 vh1 = *reinterpret_cast<const short8*>(Ah + gstage + ks * 64 + 32);
      short8 vl0 = *reinterpret_cast<const short8*>(Al + gstage + ks * 64);
      short8 vl1 = *reinterpret_cast<const short8*>(Al + gstage + ks * 64 + 32);
      __syncthreads();  // prior stage's reads complete before overwrite
      *reinterpret_cast<short8*>(&sAh[tid * 8]) = vh0;
      *reinterpret_cast<short8*>(&sAh[2048 + tid * 8]) = vh1;
      *reinterpret_cast<short8*>(&sAl[tid * 8]) = vl0;
      *reinterpret_cast<short8*>(&sAl[2048 + tid * 8]) = vl1;
      __syncthreads();
#pragma unroll
      for (int kk0 = 0; kk0 < 2; ++kk0) {
#pragma unroll
        for (int rt = 0; rt < RT; ++rt) {
          int so = kk0 * 2048 + (rt * 16 + m) * 32 + quad * 8;
          a_h[rt] = *reinterpret_cast<const short8*>(&sAh[so]);
          a_l[rt] = *reinterpret_cast<const short8*>(&sAl[so]);
        }
        int kk = ks * 2 + kk0;
#pragma unroll
        for (int ct = 0; ct < CT; ++ct) {
          size_t o = ((size_t)(ct0 + ct) * KCH + kk) * 64 + lane;
          short8 b_h = Bph[o];
          short8 b_l = Bpl[o];
#pragma unroll
          for (int rt = 0; rt < RT; ++rt) {
            acc[rt][ct] = __builtin_amdgcn_mfma_f32_16x16x32_bf16(a_h[rt], b_h, acc[rt][ct], 0, 0, 0);
            acc[rt][ct] = __builtin_amdgcn_mfma_f32_16x16x32_bf16(a_h[rt], b_l, acc[rt][ct], 0, 0, 0);
            acc[rt][ct] = __builtin_amdgcn_mfma_f32_16x16x32_bf16(a_l[rt], b_h, acc[rt][ct], 0, 0, 0);
          }
        }
      }
    } else {
#pragma unroll
      for (int kk0 = 0; kk0 < 2; ++kk0) {
        int kk = ks * 2 + kk0;
#pragma unroll
        for (int rt = 0; rt < RT; ++rt) {
          size_t aoff = (size_t)((rt0 + rt) * 16 + m) * KDIM + kk * 32 + quad * 8;
          a_h[rt] = *reinterpret_cast<const short8*>(Ah + aoff);
          a_l[rt] = *reinterpret_cast<const short8*>(Al + aoff);
        }
#pragma unroll
        for (int ct = 0; ct < CT; ++ct) {
          size_t o = ((size_t)(ct0 + ct) * KCH + kk) * 64 + lane;
          short8 b_h = Bph[o];
          short8 b_l = Bpl[o];
#pragma unroll
          for (int rt = 0; rt < RT; ++rt) {
            acc[rt][ct] = __builtin_amdgcn_mfma_f32_16x16x32_bf16(a_h[rt], b_h, acc[rt][ct], 0, 0, 0);
            acc[rt][ct] = __builtin_amdgcn_mfma_f32_16x16x32_bf16(a_h[rt], b_l, acc[rt][ct], 0, 0, 0);
            acc[rt][ct] = __builtin_amdgcn_mfma_f32_16x16x32_bf16(a_l[rt], b_h, acc[rt][ct], 0, 0, 0);
          }
        }
      }
    }
  }

  // fused attention logits: this wave's CT*16 cols lie in exactly one head
  constexpr int CPH = NOUT / HEADS;
  int head = (ct0 * 16) / CPH;
  float asl[CT], adl[CT];
#pragma unroll
  for (int ct = 0; ct < CT; ++ct) {
    asl[ct] = asv[(ct0 + ct) * 16 + m];
    adl[ct] = adv[(ct0 + ct) * 16 + m];
  }
  float ps[RT * 4], pd[RT * 4];
#pragma unroll
  for (int i = 0; i < RT * 4; ++i) { ps[i] = 0.f; pd[i] = 0.f; }
#pragma unroll
  for (int rt = 0; rt < RT; ++rt)
#pragma unroll
    for (int ct = 0; ct < CT; ++ct)
#pragma unroll
      for (int r = 0; r < 4; ++r) {
        ps[rt * 4 + r] += acc[rt][ct][r] * asl[ct];
        pd[rt * 4 + r] += acc[rt][ct][r] * adl[ct];
      }
#pragma unroll
  for (int off = 1; off < 16; off <<= 1) {
#pragma unroll
    for (int i = 0; i < RT * 4; ++i) {
      ps[i] += __shfl_xor(ps[i], off);
      pd[i] += __shfl_xor(pd[i], off);
    }
  }
  if (m == 0) {
#pragma unroll
    for (int rt = 0; rt < RT; ++rt)
#pragma unroll
      for (int r = 0; r < 4; ++r) {
        int row = (rt0 + rt) * 16 + quad * 4 + r;
        if (row < NNODES) {
          als[(size_t)row * HEADS + head] = sane(ps[rt * 4 + r], 80.f);
          ald[(size_t)row * HEADS + head] = sane(pd[rt * 4 + r], 80.f);
        }
      }
  }

  // store C (hi-only bf16, row-major for the aggregation gather)
#pragma unroll
  for (int rt = 0; rt < RT; ++rt)
#pragma unroll
    for (int ct = 0; ct < CT; ++ct)
#pragma unroll
      for (int r = 0; r < 4; ++r) {
        int row = (rt0 + rt) * 16 + quad * 4 + r;
        if (row < NNODES) {
          float v = sane(acc[rt][ct][r], 3e4f);
          Ch[(size_t)row * NOUT + (ct0 + ct) * 16 + m] = f2bf(v);
        }
      }
}

// ---------------- normalized edge weights (alpha) ----------------
// one wave per dst node; lane-per-edge; shuffle-reduce denominators
template<int H>
__global__ __launch_bounds__(256) void alpha_kernel(const int* __restrict__ row_ptr,
                                                    const int* __restrict__ csr_src,
                                                    const float* __restrict__ als,
                                                    const float* __restrict__ ald,
                                                    float* __restrict__ alpha) {
  int wid = threadIdx.x >> 6, lane = threadIdx.x & 63;
  int dst = blockIdx.x * 4 + wid;
  if (dst >= NNODES) return;
  int start = row_ptr[dst], end = row_ptr[dst + 1];
  int cnt = end - start;
  if (cnt <= 0) return;
  float adv[H];
#pragma unroll
  for (int h = 0; h < H; ++h) adv[h] = ald[(size_t)dst * H + h];

  if (cnt <= 64) {
    int i = start + lane;
    bool valid = lane < cnt;
    int s = valid ? min(max(csr_src[i], 0), NNODES - 1) : 0;
    float w[H];
#pragma unroll
    for (int h = 0; h < H; ++h) {
      float e = als[(size_t)s * H + h] + adv[h];
      e = e > 0.f ? e : 0.2f * e;
      e = fminf(fmaxf(e, -80.f), 80.f);
      w[h] = valid ? __expf(e) : 0.f;
    }
#pragma unroll
    for (int h = 0; h < H; ++h) {
      float v = w[h];
#pragma unroll
      for (int off = 1; off < 64; off <<= 1) v += __shfl_xor(v, off);
      float inv = 1.f / fmaxf(v, 1e-30f);
      if (valid) alpha[(size_t)i * H + h] = w[h] * inv;
    }
  } else {
    float dl[H];
#pragma unroll
    for (int h = 0; h < H; ++h) dl[h] = 0.f;
    for (int base = start; base < end; base += 64) {
      int i = base + lane;
      bool valid = i < end;
      int s = valid ? min(max(csr_src[i], 0), NNODES - 1) : 0;
#pragma unroll
      for (int h = 0; h < H; ++h) {
        float e = als[(size_t)s * H + h] + adv[h];
        e = e > 0.f ? e : 0.2f * e;
        e = fminf(fmaxf(e, -80.f), 80.f);
        float w = valid ? __expf(e) : 0.f;
        dl[h] += w;
        if (valid) alpha[(size_t)i * H + h] = w;
      }
    }
    float inv[H];
#pragma unroll
    for (int h = 0; h < H; ++h) {
      float v = dl[h];
#pragma unroll
      for (int off = 1; off < 64; off <<= 1) v += __shfl_xor(v, off);
      inv[h] = 1.f / fmaxf(v, 1e-30f);
    }
    for (int base = start; base < end; base += 64) {
      int i = base + lane;
      if (i < end)
#pragma unroll
        for (int h = 0; h < H; ++h) alpha[(size_t)i * H + h] *= inv[h];
    }
  }
}

// ---------------- aggregation, mid layers (T=256, H=4) ----------------
// ONE WAVE PER DST: lane owns 4 cols (uint2 8B load -> 512B/wave-instr);
// 4 edges in flight (independent chains); accumulate wave-locally; no LDS,
// no barriers. Epilogue (bias+ELU+hi/lo split) straight from registers.
__global__ __launch_bounds__(256) void agg_mid_kernel(const int* __restrict__ row_ptr,
                                                      const int* __restrict__ csr_src,
                                                      const __hip_bfloat16* __restrict__ Fh,
                                                      const float* __restrict__ alpha,
                                                      const float* __restrict__ bias,
                                                      __hip_bfloat16* __restrict__ Oh,
                                                      __hip_bfloat16* __restrict__ Ol) {
  int wid = threadIdx.x >> 6, lane = threadIdx.x & 63;
  int dst = blockIdx.x * 4 + wid;
  if (dst >= NNODES) return;
  int start = row_ptr[dst], end = row_ptr[dst + 1];
  int cnt = end - start;
  int head = lane >> 4;
  float a0 = 0.f, a1 = 0.f, a2 = 0.f, a3 = 0.f;
  int p = 0;
  for (; p + 3 < cnt; p += 4) {  // 4 edges in flight
    int e0 = start + p, e1 = e0 + 1, e2 = e0 + 2, e3 = e0 + 3;
    int s0 = csr_src[e0], s1 = csr_src[e1], s2 = csr_src[e2], s3 = csr_src[e3];
    float w0 = alpha[(size_t)e0 * 4 + head];
    float w1 = alpha[(size_t)e1 * 4 + head];
    float w2 = alpha[(size_t)e2 * 4 + head];
    float w3 = alpha[(size_t)e3 * 4 + head];
    uint2v f0 = *reinterpret_cast<const uint2v*>(Fh + (size_t)s0 * 256 + lane * 4);
    uint2v f1 = *reinterpret_cast<const uint2v*>(Fh + (size_t)s1 * 256 + lane * 4);
    uint2v f2 = *reinterpret_cast<const uint2v*>(Fh + (size_t)s2 * 256 + lane * 4);
    uint2v f3 = *reinterpret_cast<const uint2v*>(Fh + (size_t)s3 * 256 + lane * 4);
    a0 += w0 * __uint_as_float(f0.x << 16);
    a1 += w0 * __uint_as_float(f0.x & 0xffff0000u);
    a2 += w0 * __uint_as_float(f0.y << 16);
    a3 += w0 * __uint_as_float(f0.y & 0xffff0000u);
    a0 += w1 * __uint_as_float(f1.x << 16);
    a1 += w1 * __uint_as_float(f1.x & 0xffff0000u);
    a2 += w1 * __uint_as_float(f1.y << 16);
    a3 += w1 * __uint_as_float(f1.y & 0xffff0000u);
    a0 += w2 * __uint_as_float(f2.x << 16);
    a1 += w2 * __uint_as_float(f2.x & 0xffff0000u);
    a2 += w2 * __uint_as_float(f2.y << 16);
    a3 += w2 * __uint_as_float(f2.y & 0xffff0000u);
    a0 += w3 * __uint_as_float(f3.x << 16);
    a1 += w3 * __uint_as_float(f3.x & 0xffff0000u);
    a2 += w3 * __uint_as_float(f3.y << 16);
    a3 += w3 * __uint_as_float(f3.y & 0xffff0000u);
  }
  for (; p < cnt; ++p) {
    int e0 = start + p;
    int s0 = csr_src[e0];
    float w0 = alpha[(size_t)e0 * 4 + head];
    uint2v f0 = *reinterpret_cast<const uint2v*>(Fh + (size_t)s0 * 256 + lane * 4);
    a0 += w0 * __uint_as_float(f0.x << 16);
    a1 += w0 * __uint_as_float(f0.x & 0xffff0000u);
    a2 += w0 * __uint_as_float(f0.y << 16);
    a3 += w0 * __uint_as_float(f0.y & 0xffff0000u);
  }
  // epilogue: bias + ELU + hi/lo split, packed 8B stores
  floatx4 bv = *reinterpret_cast<const floatx4*>(bias + lane * 4);
  float o0 = a0 + bv.x, o1 = a1 + bv.y, o2 = a2 + bv.z, o3 = a3 + bv.w;
  o0 = o0 > 0.f ? o0 : __expf(o0) - 1.f;
  o1 = o1 > 0.f ? o1 : __expf(o1) - 1.f;
  o2 = o2 > 0.f ? o2 : __expf(o2) - 1.f;
  o3 = o3 > 0.f ? o3 : __expf(o3) - 1.f;
  float h0 = bf2f(f2bf(o0)), h1 = bf2f(f2bf(o1)), h2 = bf2f(f2bf(o2)), h3 = bf2f(f2bf(o3));
  short4v hv = (short4v){(short)bfbits(o0), (short)bfbits(o1), (short)bfbits(o2), (short)bfbits(o3)};
  short4v lv = (short4v){(short)bfbits(o0 - h0), (short)bfbits(o1 - h1),
                         (short)bfbits(o2 - h2), (short)bfbits(o3 - h3)};
  *reinterpret_cast<short4v*>(Oh + (size_t)dst * 256 + lane * 4) = hv;
  *reinterpret_cast<short4v*>(Ol + (size_t)dst * 256 + lane * 4) = lv;
}

// ---------------- aggregation, final layer (64-pad feat, 47 out, fp32) ------
__global__ void agg_final_kernel(const int* __restrict__ row_ptr,
                                 const int* __restrict__ csr_src,
                                 const __hip_bfloat16* __restrict__ Fh,
                                 const float* __restrict__ alpha,
                                 const float* __restrict__ bias,
                                 float* __restrict__ out) {
  int wid = threadIdx.x >> 6, lane = threadIdx.x & 63;
  int dst = blockIdx.x * 4 + wid;
  if (dst >= NNODES) return;
  int start = row_ptr[dst], end = row_ptr[dst + 1];
  int cnt = end - start;
  float acc = 0.f;
  int p = 0;
  for (; p + 3 < cnt; p += 4) {
    int e0 = start + p;
    int s0 = csr_src[e0], s1 = csr_src[e0 + 1], s2 = csr_src[e0 + 2], s3 = csr_src[e0 + 3];
    float w0 = alpha[e0], w1 = alpha[e0 + 1], w2 = alpha[e0 + 2], w3 = alpha[e0 + 3];
    float f0 = bf2f(Fh[(size_t)s0 * 64 + lane]);
    float f1 = bf2f(Fh[(size_t)s1 * 64 + lane]);
    float f2 = bf2f(Fh[(size_t)s2 * 64 + lane]);
    float f3 = bf2f(Fh[(size_t)s3 * 64 + lane]);
    acc += w0 * f0 + w1 * f1 + w2 * f2 + w3 * f3;
  }
  for (; p < cnt; ++p) {
    int e0 = start + p;
    acc += alpha[e0] * bf2f(Fh[(size_t)csr_src[e0] * 64 + lane]);
  }
  if (lane < 47) out[(size_t)dst * 47 + lane] = acc + bias[lane];
}

// ---------------- launch ----------------
extern "C" void kernel_launch(void* const* d_in, const int* in_sizes, int n_in,
                              void* d_out, int out_size, void* d_ws, size_t ws_size,
                              hipStream_t stream) {
  const float* x   = (const float*)d_in[0];
  const int* ei    = (const int*)d_in[1];
  const float* W1  = (const float*)d_in[2];
  const float* a1s = (const float*)d_in[3];
  const float* a1d = (const float*)d_in[4];
  const float* b1  = (const float*)d_in[5];
  const float* W2  = (const float*)d_in[6];
  const float* a2s = (const float*)d_in[7];
  const float* a2d = (const float*)d_in[8];
  const float* b2  = (const float*)d_in[9];
  const float* W3  = (const float*)d_in[10];
  const float* a3s = (const float*)d_in[11];
  const float* a3d = (const float*)d_in[12];
  const float* b3  = (const float*)d_in[13];
  float* out = (float*)d_out;
  (void)n_in; (void)in_sizes;

  char* base = (char*)d_ws;
  size_t off = 0;
  auto alloc = [&](size_t bytes) -> char* {
    off = (off + 255) & ~(size_t)255;
    char* p = base + off;
    off += bytes;
    return p;
  };
  int* deg     = (int*)alloc((size_t)NNODES * 4);
  int* cursor  = (int*)alloc((size_t)NNODES * 4);
  int* row_ptr = (int*)alloc((size_t)(NNODES + 1) * 4);
  int* csr_src = (int*)alloc((size_t)ETOT * 4);
  int* bsum    = (int*)alloc(256 * 4);
  int* boff    = (int*)alloc(256 * 4);
  float* als   = (float*)alloc((size_t)NNODES * 4 * 4);
  float* ald   = (float*)alloc((size_t)NNODES * 4 * 4);
  float* alpha = (float*)alloc((size_t)ETOT * 4 * 4);
  __hip_bfloat16* Ah = (__hip_bfloat16*)alloc((size_t)MPAD * 256 * 2);
  __hip_bfloat16* Al = (__hip_bfloat16*)alloc((size_t)MPAD * 256 * 2);
  __hip_bfloat16* Fh = (__hip_bfloat16*)alloc((size_t)NNODES * 256 * 2);
  __hip_bfloat16* wth = (__hip_bfloat16*)alloc((size_t)256 * 256 * 2);
  __hip_bfloat16* wtl = (__hip_bfloat16*)alloc((size_t)256 * 256 * 2);
  float* asv3 = (float*)alloc(64 * 4);
  float* adv3 = (float*)alloc(64 * 4);

  if (ws_size < off) {
    fill_out_kernel<<<(out_size + 255) / 256, 256, 0, stream>>>(out, out_size, 12345.f);
    return;
  }

  // CSR build (shared by all layers) — parallel 3-phase scan
  zero_int_kernel<<<(NNODES + 255) / 256, 256, 0, stream>>>(deg, NNODES);
  degree_kernel<<<(ETOT + 255) / 256, 256, 0, stream>>>(ei, deg);
  block_sum_kernel<<<NBLK, 256, 0, stream>>>(deg, bsum);
  scan_bsum_kernel<<<1, 256, 0, stream>>>(bsum, boff, row_ptr);
  emit_rowptr_kernel<<<NBLK, 256, 0, stream>>>(deg, boff, row_ptr, cursor);
  scatter_kernel<<<(ETOT + 255) / 256, 256, 0, stream>>>(ei, cursor, csr_src);

  split_input_kernel<<<(MPAD * 256 + 255) / 256, 256, 0, stream>>>(x, Ah, Al);
  pad47_kernel<<<1, 64, 0, stream>>>(a3s, a3d, asv3, adv3);

  const int grid12 = (NNODES + 63) / 64;       // 782
  const int grid3 = (NNODES + 255) / 256;      // 196
  const int gridN4 = (NNODES + 3) / 4;

  // layer 1: 128 -> 4x64, ELU
  pack_w_kernel<<<(256 * 128 + 255) / 256, 256, 0, stream>>>(W1, wth, wtl, 128, 256, 256);
  gemm_attn_kernel<128, 256, 4, 4><<<grid12, 256, 0, stream>>>(Ah, Al, wth, wtl, a1s, a1d,
                                                               Fh, als, ald);
  alpha_kernel<4><<<gridN4, 256, 0, stream>>>(row_ptr, csr_src, als, ald, alpha);
  agg_mid_kernel<<<gridN4, 256, 0, stream>>>(row_ptr, csr_src, Fh, alpha, b1, Ah, Al);

  // layer 2: 256 -> 4x64, ELU
  pack_w_kernel<<<(256 * 256 + 255) / 256, 256, 0, stream>>>(W2, wth, wtl, 256, 256, 256);
  gemm_attn_kernel<256, 256, 4, 4><<<grid12, 256, 0, stream>>>(Ah, Al, wth, wtl, a2s, a2d,
                                                               Fh, als, ald);
  alpha_kernel<4><<<gridN4, 256, 0, stream>>>(row_ptr, csr_src, als, ald, alpha);
  agg_mid_kernel<<<gridN4, 256, 0, stream>>>(row_ptr, csr_src, Fh, alpha, b2, Ah, Al);

  // layer 3: 256 -> 47 (pad 64), no ELU, fp32 out
  pack_w_kernel<<<(64 * 256 + 255) / 256, 256, 0, stream>>>(W3, wth, wtl, 256, 47, 64);
  gemm_attn_kernel<256, 64, 1, 1><<<grid3, 256, 0, stream>>>(Ah, Al, wth, wtl, asv3, adv3,
                                                             Fh, als, ald);
  alpha_kernel<1><<<gridN4, 256, 0, stream>>>(row_ptr, csr_src, als, ald, alpha);
  agg_final_kernel<<<gridN4, 256, 0, stream>>>(row_ptr, csr_src, Fh, alpha, b3, out);
}